// Round 2
// baseline (528.587 us; speedup 1.0000x reference)
//
#include <hip/hip_runtime.h>

// LoRA forward: out = 0.25 * (x @ (A*sA)^T) @ (B*sB)^T
// x: [16384, 4096] f32, A: [64, 4096] f32, B: [4096, 64] f32.
// Fused, barrier-free design: one wave owns 16 rows end-to-end.
//   Phase 1: h(16x64) = x @ A_dq^T, x loaded straight into MFMA A-fragment
//            layout from global (8 contiguous floats/lane), bf16-converted in
//            regs; A_dq fragments from L2. Register ping-pong, no __shared__
//            staging -> no vmcnt(0) barrier drains (the R0 latency bug).
//   Phase 2: h stays on-chip; one 2.5KB LDS round-trip transposes C-layout ->
//            A-operand layout; then stream out columns 64 at a time.
// Traffic: read 256MB x + write 256MB out (floor ~81us @6.3TB/s); A/B/h cached.

#define M_TOTAL 16384
#define DIN     4096
#define DOUT    4096
#define RANK    64

typedef __bf16 bf16_8 __attribute__((ext_vector_type(8)));
typedef __bf16 bf16_4 __attribute__((ext_vector_type(4)));
typedef float  f32x4  __attribute__((ext_vector_type(4)));

// ---------------- prep: dequantize A and B into bf16 ----------------
__global__ __launch_bounds__(256) void prep_kernel(
    const float* __restrict__ A, const float* __restrict__ Bm,
    const float* __restrict__ sA, const float* __restrict__ sB,
    __bf16* __restrict__ Abf, __bf16* __restrict__ Bbf) {
  int i = (blockIdx.x * 256 + threadIdx.x) * 4;
  float4 a = *(const float4*)(A + i);
  float sa = sA[i >> 12];                 // A row = i / 4096
  bf16_4 va;
  va[0] = (__bf16)(a.x * sa); va[1] = (__bf16)(a.y * sa);
  va[2] = (__bf16)(a.z * sa); va[3] = (__bf16)(a.w * sa);
  *(bf16_4*)(Abf + i) = va;

  float4 b = *(const float4*)(Bm + i);
  float sb = sB[i >> 6] * 0.25f;          // B row = i / 64; fold SCALING
  bf16_4 vb;
  vb[0] = (__bf16)(b.x * sb); vb[1] = (__bf16)(b.y * sb);
  vb[2] = (__bf16)(b.z * sb); vb[3] = (__bf16)(b.w * sb);
  *(bf16_4*)(Bbf + i) = vb;
}

// ---------------- fused LoRA kernel: one wave per 16 rows ----------------
// load a 64-wide k-chunk: x (4 x float4) + A_dq frags (8 x bf16_8)
#define LOAD_CHUNK(XV, AV, K0)                                                 \
  {                                                                            \
    XV[0] = *(const float4*)(xg + (K0));                                       \
    XV[1] = *(const float4*)(xg + (K0) + 4);                                   \
    XV[2] = *(const float4*)(xg + (K0) + 32);                                  \
    XV[3] = *(const float4*)(xg + (K0) + 36);                                  \
    _Pragma("unroll") for (int nt = 0; nt < 4; ++nt) {                         \
      AV[nt]     = *(const bf16_8*)(agl + nt * 16 * DIN + (K0));               \
      AV[4 + nt] = *(const bf16_8*)(agl + nt * 16 * DIN + (K0) + 32);          \
    }                                                                          \
  }

#define COMPUTE_CHUNK(XV, AV)                                                  \
  {                                                                            \
    _Pragma("unroll") for (int kc = 0; kc < 2; ++kc) {                         \
      float4 u = XV[kc * 2], v = XV[kc * 2 + 1];                               \
      bf16_8 af;                                                               \
      af[0] = (__bf16)u.x; af[1] = (__bf16)u.y;                                \
      af[2] = (__bf16)u.z; af[3] = (__bf16)u.w;                                \
      af[4] = (__bf16)v.x; af[5] = (__bf16)v.y;                                \
      af[6] = (__bf16)v.z; af[7] = (__bf16)v.w;                                \
      _Pragma("unroll") for (int nt = 0; nt < 4; ++nt)                         \
        hacc[nt] = __builtin_amdgcn_mfma_f32_16x16x32_bf16(                    \
            af, AV[kc * 4 + nt], hacc[nt], 0, 0, 0);                           \
    }                                                                          \
  }

// load B_dq frags for a 64-col out chunk starting at NC
#define LOAD_B(BV, NC)                                                         \
  {                                                                            \
    _Pragma("unroll") for (int nt = 0; nt < 4; ++nt) {                         \
      BV[nt * 2]     = *(const bf16_8*)(bg + ((NC) + nt * 16) * RANK);         \
      BV[nt * 2 + 1] = *(const bf16_8*)(bg + ((NC) + nt * 16) * RANK + 32);    \
    }                                                                          \
  }

#define COMPUTE_STORE(BV, NC)                                                  \
  {                                                                            \
    f32x4 acc[4];                                                              \
    _Pragma("unroll") for (int nt = 0; nt < 4; ++nt)                           \
        acc[nt] = (f32x4){0.f, 0.f, 0.f, 0.f};                                 \
    _Pragma("unroll") for (int nt = 0; nt < 4; ++nt) {                         \
      acc[nt] = __builtin_amdgcn_mfma_f32_16x16x32_bf16(                       \
          hf0, BV[nt * 2], acc[nt], 0, 0, 0);                                  \
      acc[nt] = __builtin_amdgcn_mfma_f32_16x16x32_bf16(                       \
          hf1, BV[nt * 2 + 1], acc[nt], 0, 0, 0);                              \
    }                                                                          \
    _Pragma("unroll") for (int nt = 0; nt < 4; ++nt)                           \
      _Pragma("unroll") for (int i = 0; i < 4; ++i)                            \
        og[(size_t)i * DOUT + (NC) + nt * 16] = acc[nt][i];                    \
  }

__global__ __launch_bounds__(64) void fused_kernel(
    const float* __restrict__ x, const __bf16* __restrict__ Abf,
    const __bf16* __restrict__ Bbf, float* __restrict__ out) {
  __shared__ __bf16 hs[16 * 80];   // 16 rows x 64 ranks, pad 80 (16B-aligned rows)

  const int lane = threadIdx.x;
  const int lr   = lane & 15;
  const int quad = lane >> 4;
  const int mBase = blockIdx.x * 16;

  const float*  xg  = x   + (size_t)(mBase + lr) * DIN + quad * 8;
  const __bf16* agl = Abf + (size_t)lr * DIN + quad * 8;

  f32x4 hacc[4];
#pragma unroll
  for (int nt = 0; nt < 4; ++nt) hacc[nt] = (f32x4){0.f, 0.f, 0.f, 0.f};

  // ---- phase 1: h = x @ A_dq^T over K=4096, 64-wide chunks, ping-pong ----
  float4 xva[4], xvb[4];
  bf16_8 ava[8], avb[8];
  LOAD_CHUNK(xva, ava, 0);
  LOAD_CHUNK(xvb, avb, 64);
  for (int k0 = 0; k0 < DIN; k0 += 128) {
    COMPUTE_CHUNK(xva, ava);
    if (k0 + 128 < DIN) LOAD_CHUNK(xva, ava, k0 + 128);
    COMPUTE_CHUNK(xvb, avb);
    if (k0 + 192 < DIN) LOAD_CHUNK(xvb, avb, k0 + 192);
  }

  // ---- transpose h: C-layout (row=quad*4+i, col=lr per 16-tile) -> A-layout
#pragma unroll
  for (int nt = 0; nt < 4; ++nt)
#pragma unroll
    for (int i = 0; i < 4; ++i)
      hs[(quad * 4 + i) * 80 + nt * 16 + lr] = (__bf16)hacc[nt][i];
  __syncthreads();   // single wave: just a waitcnt+barrier, once
  const bf16_8 hf0 = *(const bf16_8*)&hs[lr * 80 + quad * 8];
  const bf16_8 hf1 = *(const bf16_8*)&hs[lr * 80 + 32 + quad * 8];

  // ---- phase 2: out rows = h @ B_dq^T, 64 cols per step, ping-pong ----
  const __bf16* bg = Bbf + (size_t)lr * RANK + quad * 8;
  float*        og = out + (size_t)(mBase + quad * 4) * DOUT + lr;

  bf16_8 bva[8], bvb[8];
  LOAD_B(bva, 0);
  for (int nc = 0; nc < DOUT; nc += 128) {
    LOAD_B(bvb, nc + 64);
    COMPUTE_STORE(bva, nc);
    if (nc + 128 < DOUT) LOAD_B(bva, nc + 128);
    COMPUTE_STORE(bvb, nc + 64);
  }
}

extern "C" void kernel_launch(void* const* d_in, const int* in_sizes, int n_in,
                              void* d_out, int out_size, void* d_ws, size_t ws_size,
                              hipStream_t stream) {
  const float* x  = (const float*)d_in[0];
  const float* A  = (const float*)d_in[1];
  const float* Bm = (const float*)d_in[2];
  const float* sA = (const float*)d_in[3];
  const float* sB = (const float*)d_in[4];
  float* out = (float*)d_out;

  // workspace: Abf (512 KB) | Bbf (512 KB)
  __bf16* Abf = (__bf16*)d_ws;
  __bf16* Bbf = Abf + (size_t)RANK * DIN;

  prep_kernel<<<256, 256, 0, stream>>>(A, Bm, sA, sB, Abf, Bbf);
  fused_kernel<<<M_TOTAL / 16, 64, 0, stream>>>(x, Abf, Bbf, out);
}